// Round 5
// baseline (324.255 us; speedup 1.0000x reference)
//
#include <hip/hip_runtime.h>

typedef unsigned long long ull;

constexpr int N   = 500;
constexpr int HW  = 60800;    // 200*304
constexpr int NW  = 950;      // HW/64 (exact)
constexpr int NC  = 80;       // num classes
constexpr int NTILES = N * NW / 4;   // 118,750 pack tiles (256 px each)
constexpr int PB  = 1024;     // pack blocks (block 0 does the sort instead)
constexpr int G   = PB + 1;   // total blocks in k_fused
constexpr int TAIL = 64;      // last-arriving blocks run the IoU phase
constexpr int QPB = (HW / 4 + 255) / 256;   // 60 blocks of quads per instance

// ---------------------------------------------------------------------------
// Fused: pack (blocks 1..PB) || sort+CSR+pairs (block 0)  ->  [last 64
// arrivals] IoU per pair  ->  [last IoU block] decay + final sort.
__global__ void __launch_bounds__(512)
k_fused(const float* __restrict__ mp, const int* __restrict__ labels,
        const float* __restrict__ scores,
        ull* __restrict__ packed, int* __restrict__ order_g,
        float* __restrict__ scoresS_g, int* __restrict__ labelsS_g,
        int* __restrict__ offs_g, int* __restrict__ members_g,
        int2* __restrict__ pairList, int* __restrict__ pairCount_g,
        float* __restrict__ iou, int* __restrict__ done1, int* __restrict__ done2,
        float* __restrict__ outScores, float* __restrict__ outLabels,
        float* __restrict__ outKeep, int* __restrict__ keepOrig_g) {
    const int t    = threadIdx.x;
    const int lane = t & 63;

    __shared__ float fbufA[N];        // sS   | compS
    __shared__ float fbufB[N];        // sdec
    __shared__ int   ibufA[N];        // orderS -> members | members(decay)
    __shared__ int   ibufB[N];        // labS (both phases)
    __shared__ int   ibufC[NC + 1];   // offs
    __shared__ int   cntS[NC];
    __shared__ int   pcnt;
    __shared__ int   role;            // tail rank or -1
    __shared__ int   isLast;

    // ---------------- Phase A: pack || sort ----------------
    if (blockIdx.x != 0) {
        int wid = (blockIdx.x - 1) * 8 + (t >> 6);
        for (int tile = wid; tile < NTILES; tile += PB * 8) {
            size_t base = (size_t)tile * 256;
            float v0 = mp[base +   0 + lane];
            float v1 = mp[base +  64 + lane];
            float v2 = mp[base + 128 + lane];
            float v3 = mp[base + 192 + lane];
            ull b0 = __ballot(v0 > 0.5f);
            ull b1 = __ballot(v1 > 0.5f);
            ull b2 = __ballot(v2 > 0.5f);
            ull b3 = __ballot(v3 > 0.5f);
            if (lane == 0) {
                longlong4 w;
                w.x = (long long)b0; w.y = (long long)b1;
                w.z = (long long)b2; w.w = (long long)b3;
                *(longlong4*)(packed + tile * 4) = w;
            }
        }
    } else {
        float* sS     = fbufA;
        int*   orderS = ibufA;
        int*   labS   = ibufB;
        int*   offs   = ibufC;
        if (t < N) sS[t] = scores[t];
        if (t < NC) cntS[t] = 0;
        if (t == 0) pcnt = 0;
        __syncthreads();
        if (t < N) {                       // stable descending rank sort
            float si = sS[t];
            int rank = 0;
            for (int j = 0; j < N; ++j) {
                float sj = sS[j];
                if (sj > si || (sj == si && j < t)) rank++;
            }
            orderS[rank] = t;
        }
        __syncthreads();
        int myLab = -1;
        if (t < N) {
            int o = orderS[t];
            order_g[t]   = o;
            scoresS_g[t] = sS[o];
            myLab = labels[o];
            labS[t] = myLab;
            labelsS_g[t] = myLab;
        }
        __syncthreads();
        if (t < N) atomicAdd(&cntS[myLab], 1);
        __syncthreads();
        if (t == 0) {
            int s = 0;
            for (int c = 0; c < NC; ++c) { offs[c] = s; s += cntS[c]; }
            offs[NC] = s;
        }
        __syncthreads();
        if (t < NC) cntS[t] = offs[t];     // insertion cursors
        __syncthreads();
        int* members = ibufA;              // orderS dead now; reuse
        if (t < N) { int p = atomicAdd(&cntS[myLab], 1); members[p] = t; }
        __syncthreads();
        if (t < NC) {                      // enumerate same-class pairs (i<j)
            int b = offs[t], e = offs[t + 1];
            for (int a = b; a < e; ++a)
                for (int c2 = a + 1; c2 < e; ++c2) {
                    int i = members[a], j = members[c2];
                    int lo = min(i, j), hi = max(i, j);
                    int p = atomicAdd(&pcnt, 1);
                    pairList[p] = make_int2(lo, hi);
                }
        }
        __syncthreads();
        if (t <= NC) offs_g[t] = offs[t];
        if (t < N)   members_g[t] = members[t];
        if (t == 0)  *pairCount_g = pcnt;
    }

    // ---------------- Ticket 1: last TAIL arrivals continue ----------------
    __threadfence();                       // release this thread's writes
    __syncthreads();
    if (t == 0) {
        int old = __hip_atomic_fetch_add(done1, 1, __ATOMIC_ACQ_REL,
                                         __HIP_MEMORY_SCOPE_AGENT);
        int r = old - (G - TAIL);
        if (r >= 0) {                      // wait for every block to arrive
            while (__hip_atomic_load(done1, __ATOMIC_RELAXED,
                                     __HIP_MEMORY_SCOPE_AGENT) < G)
                __builtin_amdgcn_s_sleep(2);
        }
        role = r;
    }
    __syncthreads();
    if (role < 0) return;
    __threadfence();                       // acquire all blocks' writes

    // ---------------- Phase B: IoU per pair (wave per pair) ----------------
    {
        int gw = role * 8 + (t >> 6);
        int np = *pairCount_g;
        for (int p = gw; p < np; p += TAIL * 8) {
            int2 pr = pairList[p];
            const ull* A = packed + (size_t)order_g[pr.x] * NW;
            const ull* B = packed + (size_t)order_g[pr.y] * NW;
            ull acc = 0;  // inter | areaA<<21 | areaB<<42  (fields < 2^17)
            for (int w = lane; w < NW; w += 64) {
                ull a = A[w], b = B[w];
                acc += (ull)__popcll(a & b)
                     + ((ull)__popcll(a) << 21)
                     + ((ull)__popcll(b) << 42);
            }
#pragma unroll
            for (int off = 32; off > 0; off >>= 1) acc += __shfl_down(acc, off, 64);
            if (lane == 0) {
                float inter = (float)(int)(acc & 0x1FFFFF);
                float areaA = (float)(int)((acc >> 21) & 0x1FFFFF);
                float areaB = (float)(int)((acc >> 42) & 0x1FFFFF);
                float uni   = areaA + areaB - inter;   // exact small ints
                iou[pr.x * N + pr.y] = inter / uni;
            }
        }
    }

    // ---------------- Ticket 2: last IoU block runs decay ----------------
    __threadfence();
    __syncthreads();
    if (t == 0) {
        int old2 = __hip_atomic_fetch_add(done2, 1, __ATOMIC_ACQ_REL,
                                          __HIP_MEMORY_SCOPE_AGENT);
        isLast = (old2 == TAIL - 1);
    }
    __syncthreads();
    if (!isLast) return;
    __threadfence();                       // acquire all IoU writes

    // ---------------- Phase C: decay + final stable sort ----------------
    {
        int*   labS    = ibufB;
        int*   members = ibufA;
        int*   offs    = ibufC;
        float* compS   = fbufA;
        float* sdec    = fbufB;
        if (t < N)  { labS[t] = labelsS_g[t]; members[t] = members_g[t]; }
        if (t <= NC) offs[t] = offs_g[t];
        __syncthreads();
        if (t < N) {                       // comp[j] = max_{i<j same class} iou
            int lj = labS[t];
            float m = 0.f;
            int b = offs[lj], e = offs[lj + 1];
            for (int q = b; q < e; ++q) {
                int i = members[q];
                if (i < t) m = fmaxf(m, iou[i * N + t]);
            }
            compS[t] = m;
        }
        __syncthreads();
        if (t < N) {                       // coefficient (1 bounds the min)
            int lj = labS[t];
            float c = 1.f;
            int b = offs[lj], e = offs[lj + 1];
            for (int q = b; q < e; ++q) {
                int i = members[q];
                if (i < t) {
                    float d  = iou[i * N + t];
                    float ci = compS[i];
                    c = fminf(c, expf(-2.f * d * d) / expf(-2.f * ci * ci));  // mirror np
                }
            }
            sdec[t] = scoresS_g[t] * c;
        }
        __syncthreads();
        if (t < N) {                       // stable descending rank on decayed scores
            float sj = sdec[t];
            int rank = 0;
            for (int i = 0; i < N; ++i) {
                float si = sdec[i];
                if (si > sj || (si == sj && i < t)) rank++;
            }
            int o = order_g[t];
            outScores[rank]  = sj;
            outLabels[rank]  = (float)labS[t];
            outKeep[rank]    = (float)o;
            keepOrig_g[rank] = o;
        }
    }
}

// ---------------------------------------------------------------------------
// Expand kept masks to float output. 2D grid: y = output instance (no div).
__global__ void k_gather(const ull* __restrict__ packed, const int* __restrict__ keepOrig,
                         float4* __restrict__ outMasks) {
    int q = blockIdx.x * blockDim.x + threadIdx.x;   // quad within instance
    if (q >= HW / 4) return;
    int k    = blockIdx.y;
    int orig = keepOrig[k];                          // uniform -> scalar load
    int pix  = q * 4;
    ull w  = packed[(size_t)orig * NW + (pix >> 6)];
    int sh = pix & 63;
    float4 r;
    r.x = (float)((w >> (sh    )) & 1ULL);
    r.y = (float)((w >> (sh + 1)) & 1ULL);
    r.z = (float)((w >> (sh + 2)) & 1ULL);
    r.w = (float)((w >> (sh + 3)) & 1ULL);
    outMasks[(size_t)k * (HW / 4) + q] = r;
}

// ---------------------------------------------------------------------------
extern "C" void kernel_launch(void* const* d_in, const int* in_sizes, int n_in,
                              void* d_out, int out_size, void* d_ws, size_t ws_size,
                              hipStream_t stream) {
    const float* mask_preds = (const float*)d_in[0];
    const int*   labels     = (const int*)d_in[1];
    const float* scores     = (const float*)d_in[2];

    float*  o         = (float*)d_out;
    float*  outScores = o;
    float*  outLabels = o + N;
    float4* outMasks  = (float4*)(o + 2 * N);
    float*  outKeep   = o + 2 * N + (size_t)N * HW;

    // workspace carve-up (16B-aligned chunks; ~5.8 MB total)
    char* w = (char*)d_ws;
    ull*   packed     = (ull*)w;   w += (size_t)N * NW * 8;            // 3,800,000
    int*   order_g    = (int*)w;   w += N * 4;
    float* scoresS_g  = (float*)w; w += N * 4;
    int*   labelsS_g  = (int*)w;   w += N * 4;
    int*   offs_g     = (int*)w;   w += (NC + 4) * 4;
    int*   members_g  = (int*)w;   w += N * 4;
    int*   keepOrig_g = (int*)w;   w += N * 4;
    int*   counters   = (int*)w;   w += 128;   // done1, done2, pairCount
    float* iou        = (float*)w; w += (size_t)N * N * 4;             // 1,000,000
    int2*  pairList   = (int2*)w;  /* N*(N-1)/2 * 8 = 998,000 */

    int* done1     = counters;
    int* done2     = counters + 1;
    int* pairCount = counters + 2;

    hipMemsetAsync(counters, 0, 128, stream);   // fresh tickets every call

    hipLaunchKernelGGL(k_fused, dim3(G), dim3(512), 0, stream,
                       mask_preds, labels, scores, packed, order_g,
                       scoresS_g, labelsS_g, offs_g, members_g, pairList, pairCount,
                       iou, done1, done2,
                       outScores, outLabels, outKeep, keepOrig_g);
    hipLaunchKernelGGL(k_gather, dim3(QPB, N), dim3(256), 0, stream,
                       packed, keepOrig_g, outMasks);
}

// Round 6
// 110.595 us; speedup vs baseline: 2.9319x; 2.9319x over previous
//
#include <hip/hip_runtime.h>

typedef unsigned long long ull;

constexpr int N   = 500;
constexpr int HW  = 60800;    // 200*304
constexpr int NW  = 950;      // HW/64 (exact)
constexpr int NC  = 80;       // num classes
constexpr int NTILES = N * NW / 4;   // 118,750 pack tiles (256 px each)
constexpr int PB  = 1024;     // pack blocks (block 0 does the sort instead)
constexpr int NB2 = 576;      // node-2 blocks (all co-resident: <= 4/CU * 256)
constexpr int IOUB = 64;      // node-2 blocks that take IoU duty

// ---------------------------------------------------------------------------
// Node 1. Block 0: stable score sort + per-class CSR + same-class pair list +
// counter/keepOrig init.  Blocks 1..PB: binarize + bit-pack mask_preds.
__global__ void __launch_bounds__(512)
k_packsort(const float* __restrict__ mp, const int* __restrict__ labels,
           const float* __restrict__ scores,
           ull* __restrict__ packed, int* __restrict__ order_g,
           float* __restrict__ scoresS_g, int* __restrict__ labelsS_g,
           int* __restrict__ offs_g, int* __restrict__ members_g,
           int2* __restrict__ pairList, int* __restrict__ counters,
           int* __restrict__ keepOrig_g) {
    const int t    = threadIdx.x;
    const int lane = t & 63;

    if (blockIdx.x != 0) {
        // ---- pack ----
        int wid = (blockIdx.x - 1) * 8 + (t >> 6);
        for (int tile = wid; tile < NTILES; tile += PB * 8) {
            size_t base = (size_t)tile * 256;
            float v0 = mp[base +   0 + lane];
            float v1 = mp[base +  64 + lane];
            float v2 = mp[base + 128 + lane];
            float v3 = mp[base + 192 + lane];
            ull b0 = __ballot(v0 > 0.5f);
            ull b1 = __ballot(v1 > 0.5f);
            ull b2 = __ballot(v2 > 0.5f);
            ull b3 = __ballot(v3 > 0.5f);
            if (lane == 0) {
                longlong4 w;
                w.x = (long long)b0; w.y = (long long)b1;
                w.z = (long long)b2; w.w = (long long)b3;
                *(longlong4*)(packed + tile * 4) = w;
            }
        }
        return;
    }

    // ---- block 0: init + sort + CSR + pairs ----
    __shared__ float sS[N];
    __shared__ int   orderS[N];
    __shared__ int   labS[N];
    __shared__ int   cnt[NC];
    __shared__ int   offs[NC + 1];
    __shared__ int   members[N];
    __shared__ int   pcnt;

    if (t < N) keepOrig_g[t] = -1;     // "not ready" sentinel for node-2 spin
    if (t < 3) counters[t] = 0;        // ticket1, ticket2, wq
    if (t < N) sS[t] = scores[t];
    if (t < NC) cnt[t] = 0;
    if (t == 0) pcnt = 0;
    __syncthreads();
    if (t < N) {                       // stable descending rank sort
        float si = sS[t];
        int rank = 0;
        for (int j = 0; j < N; ++j) {
            float sj = sS[j];
            if (sj > si || (sj == si && j < t)) rank++;
        }
        orderS[rank] = t;
    }
    __syncthreads();
    int myLab = -1;
    if (t < N) {
        int o = orderS[t];
        order_g[t]   = o;
        scoresS_g[t] = sS[o];
        myLab = labels[o];
        labS[t] = myLab;
        labelsS_g[t] = myLab;
    }
    __syncthreads();
    if (t < N) atomicAdd(&cnt[myLab], 1);
    __syncthreads();
    if (t == 0) {
        int s = 0;
        for (int c = 0; c < NC; ++c) { offs[c] = s; s += cnt[c]; }
        offs[NC] = s;
    }
    __syncthreads();
    if (t < NC) cnt[t] = offs[t];      // insertion cursors
    __syncthreads();
    if (t < N) { int p = atomicAdd(&cnt[myLab], 1); members[p] = t; }
    __syncthreads();
    if (t < NC) {                      // enumerate same-class pairs (i<j)
        int b = offs[t], e = offs[t + 1];
        for (int a = b; a < e; ++a)
            for (int c2 = a + 1; c2 < e; ++c2) {
                int i = members[a], j = members[c2];
                int lo = min(i, j), hi = max(i, j);
                int p = atomicAdd(&pcnt, 1);
                pairList[p] = make_int2(lo, hi);
            }
    }
    __syncthreads();
    if (t <= NC) offs_g[t] = offs[t];
    if (t < N)   members_g[t] = members[t];
    if (t == 0)  counters[3] = pcnt;   // pairCount
}

// ---------------------------------------------------------------------------
// Node 2. Ticketed roles, NO fences: first 64 arrivals compute IoU (atomic
// LLC stores), last IoU block runs decay + final sort (atomic LLC loads),
// then everyone drains the gather work queue (value-spin on keepOrig[k]).
__global__ void __launch_bounds__(512)
k_iougather(const ull* __restrict__ packed, const int* __restrict__ order_g,
            const float* __restrict__ scoresS_g, const int* __restrict__ labelsS_g,
            const int* __restrict__ offs_g, const int* __restrict__ members_g,
            const int2* __restrict__ pairList, int* __restrict__ counters,
            int* __restrict__ iouI, int* __restrict__ keepOrig_g,
            float* __restrict__ outScores, float* __restrict__ outLabels,
            float* __restrict__ outKeep, float4* __restrict__ outMasks) {
    const int t    = threadIdx.x;
    const int lane = t & 63;
    int* ticket1 = counters + 0;
    int* ticket2 = counters + 1;
    int* wq      = counters + 2;

    __shared__ int sRole, sLast, sUnit, sOrig;

    if (t == 0) sRole = __hip_atomic_fetch_add(ticket1, 1, __ATOMIC_RELAXED,
                                               __HIP_MEMORY_SCOPE_AGENT);
    __syncthreads();

    if (sRole < IOUB) {
        // ---- IoU stripes (wave per pair) ----
        int np = counters[3];          // node-1 data, never changes in node 2
        for (int p = sRole * 8 + (t >> 6); p < np; p += IOUB * 8) {
            int2 pr = pairList[p];
            const ull* A = packed + (size_t)order_g[pr.x] * NW;
            const ull* B = packed + (size_t)order_g[pr.y] * NW;
            ull acc = 0;  // inter | areaA<<21 | areaB<<42  (fields < 2^17)
            for (int w = lane; w < NW; w += 64) {
                ull a = A[w], b = B[w];
                acc += (ull)__popcll(a & b)
                     + ((ull)__popcll(a) << 21)
                     + ((ull)__popcll(b) << 42);
            }
#pragma unroll
            for (int off = 32; off > 0; off >>= 1) acc += __shfl_down(acc, off, 64);
            if (lane == 0) {
                float inter = (float)(int)(acc & 0x1FFFFF);
                float areaA = (float)(int)((acc >> 21) & 0x1FFFFF);
                float areaB = (float)(int)((acc >> 42) & 0x1FFFFF);
                float uni   = areaA + areaB - inter;    // exact small ints
                __hip_atomic_store(iouI + pr.x * N + pr.y,
                                   __float_as_int(inter / uni),
                                   __ATOMIC_RELAXED, __HIP_MEMORY_SCOPE_AGENT);
            }
        }
        asm volatile("s_waitcnt vmcnt(0)" ::: "memory");  // stores at LLC
        __syncthreads();                                   // all waves drained
        if (t == 0) sLast = __hip_atomic_fetch_add(ticket2, 1, __ATOMIC_RELAXED,
                                                   __HIP_MEMORY_SCOPE_AGENT);
        __syncthreads();

        if (sLast == IOUB - 1) {
            // ---- decay + final stable sort (single block) ----
            __shared__ int   labS[N];
            __shared__ float compS[N];
            __shared__ float sdec[N];
            __shared__ int   offs[NC + 1];
            __shared__ int   members[N];
            if (t < N)  { labS[t] = labelsS_g[t]; members[t] = members_g[t]; }
            if (t <= NC) offs[t] = offs_g[t];
            __syncthreads();
            if (t < N) {                    // comp[j] = max_{i<j same class} iou
                int lj = labS[t];
                float m = 0.f;
                int b = offs[lj], e = offs[lj + 1];
                for (int q = b; q < e; ++q) {
                    int i = members[q];
                    if (i < t) {
                        float v = __int_as_float(__hip_atomic_load(
                            iouI + i * N + t, __ATOMIC_RELAXED,
                            __HIP_MEMORY_SCOPE_AGENT));
                        m = fmaxf(m, v);
                    }
                }
                compS[t] = m;
            }
            __syncthreads();
            if (t < N) {                    // coefficient (1 bounds the min)
                int lj = labS[t];
                float c = 1.f;
                int b = offs[lj], e = offs[lj + 1];
                for (int q = b; q < e; ++q) {
                    int i = members[q];
                    if (i < t) {
                        float d = __int_as_float(__hip_atomic_load(
                            iouI + i * N + t, __ATOMIC_RELAXED,
                            __HIP_MEMORY_SCOPE_AGENT));
                        float ci = compS[i];
                        c = fminf(c, expf(-2.f * d * d) / expf(-2.f * ci * ci));
                    }
                }
                sdec[t] = scoresS_g[t] * c;
            }
            __syncthreads();
            if (t < N) {                    // stable descending rank
                float sj = sdec[t];
                int rank = 0;
                for (int i = 0; i < N; ++i) {
                    float si = sdec[i];
                    if (si > sj || (si == sj && i < t)) rank++;
                }
                int o = order_g[t];
                outScores[rank] = sj;
                outLabels[rank] = (float)labS[t];
                outKeep[rank]   = (float)o;
                __hip_atomic_store(keepOrig_g + rank, o, __ATOMIC_RELAXED,
                                   __HIP_MEMORY_SCOPE_AGENT);   // releases spinners
            }
            __syncthreads();
        }
    }

    // ---- gather work queue: one output instance per unit ----
    for (;;) {
        if (t == 0) sUnit = __hip_atomic_fetch_add(wq, 1, __ATOMIC_RELAXED,
                                                   __HIP_MEMORY_SCOPE_AGENT);
        __syncthreads();
        int k = sUnit;
        if (k >= N) break;                 // uniform exit
        if (t == 0) {
            int v;
            while ((v = __hip_atomic_load(keepOrig_g + k, __ATOMIC_RELAXED,
                                          __HIP_MEMORY_SCOPE_AGENT)) < 0)
                __builtin_amdgcn_s_sleep(16);
            sOrig = v;
        }
        __syncthreads();
        int orig = sOrig;
        const ull* row = packed + (size_t)orig * NW;
        float4*    dst = outMasks + (size_t)k * (HW / 4);
        for (int q = t; q < HW / 4; q += 512) {
            int pix = q * 4;
            ull w  = row[pix >> 6];
            int sh = pix & 63;
            float4 r;
            r.x = (float)((w >> (sh    )) & 1ULL);
            r.y = (float)((w >> (sh + 1)) & 1ULL);
            r.z = (float)((w >> (sh + 2)) & 1ULL);
            r.w = (float)((w >> (sh + 3)) & 1ULL);
            dst[q] = r;
        }
        __syncthreads();                   // nobody re-reads sUnit/sOrig early
    }
}

// ---------------------------------------------------------------------------
extern "C" void kernel_launch(void* const* d_in, const int* in_sizes, int n_in,
                              void* d_out, int out_size, void* d_ws, size_t ws_size,
                              hipStream_t stream) {
    const float* mask_preds = (const float*)d_in[0];
    const int*   labels     = (const int*)d_in[1];
    const float* scores     = (const float*)d_in[2];

    float*  o         = (float*)d_out;
    float*  outScores = o;
    float*  outLabels = o + N;
    float4* outMasks  = (float4*)(o + 2 * N);
    float*  outKeep   = o + 2 * N + (size_t)N * HW;

    // workspace carve-up (16B-aligned chunks; ~5.8 MB total)
    char* w = (char*)d_ws;
    ull*   packed     = (ull*)w;   w += (size_t)N * NW * 8;            // 3,800,000
    int*   order_g    = (int*)w;   w += N * 4;
    float* scoresS_g  = (float*)w; w += N * 4;
    int*   labelsS_g  = (int*)w;   w += N * 4;
    int*   offs_g     = (int*)w;   w += (NC + 4) * 4;
    int*   members_g  = (int*)w;   w += N * 4;
    int*   keepOrig_g = (int*)w;   w += N * 4;
    int*   counters   = (int*)w;   w += 128;   // ticket1, ticket2, wq, pairCount
    int*   iouI       = (int*)w;   w += (size_t)N * N * 4;             // 1,000,000
    int2*  pairList   = (int2*)w;  /* N*(N-1)/2 * 8 = 998,000 */

    hipLaunchKernelGGL(k_packsort, dim3(PB + 1), dim3(512), 0, stream,
                       mask_preds, labels, scores, packed, order_g,
                       scoresS_g, labelsS_g, offs_g, members_g, pairList,
                       counters, keepOrig_g);
    hipLaunchKernelGGL(k_iougather, dim3(NB2), dim3(512), 0, stream,
                       packed, order_g, scoresS_g, labelsS_g, offs_g, members_g,
                       pairList, counters, iouI, keepOrig_g,
                       outScores, outLabels, outKeep, outMasks);
}

// Round 8
// 103.680 us; speedup vs baseline: 3.1275x; 1.0667x over previous
//
#include <hip/hip_runtime.h>

typedef unsigned long long ull;
typedef float f32x4 __attribute__((ext_vector_type(4)));

constexpr int N   = 500;
constexpr int HW  = 60800;    // 200*304
constexpr int NW  = 950;      // HW/64 (exact)
constexpr int NC  = 80;       // num classes
constexpr int NTILES = N * NW / 4;   // 118,750 pack tiles (256 px each)
constexpr int PB  = 1024;     // pack blocks (block 0 does the sort instead)
constexpr int IOUB = 64;      // IoU blocks in node 2
constexpr int QPB = (HW / 4 + 255) / 256;   // 60 blocks of quads per instance

// ---------------------------------------------------------------------------
// Node 1. Block 0: stable score sort + per-class CSR + same-class pair list +
// ticket init.  Blocks 1..PB: binarize + bit-pack mask_preds.
__global__ void __launch_bounds__(512)
k_packsort(const float* __restrict__ mp, const int* __restrict__ labels,
           const float* __restrict__ scores,
           ull* __restrict__ packed, int* __restrict__ order_g,
           float* __restrict__ scoresS_g, int* __restrict__ labelsS_g,
           int* __restrict__ offs_g, int* __restrict__ members_g,
           int2* __restrict__ pairList, int* __restrict__ counters) {
    const int t    = threadIdx.x;
    const int lane = t & 63;

    if (blockIdx.x != 0) {
        // ---- pack ----
        int wid = (blockIdx.x - 1) * 8 + (t >> 6);
        for (int tile = wid; tile < NTILES; tile += PB * 8) {
            size_t base = (size_t)tile * 256;
            float v0 = mp[base +   0 + lane];
            float v1 = mp[base +  64 + lane];
            float v2 = mp[base + 128 + lane];
            float v3 = mp[base + 192 + lane];
            ull b0 = __ballot(v0 > 0.5f);
            ull b1 = __ballot(v1 > 0.5f);
            ull b2 = __ballot(v2 > 0.5f);
            ull b3 = __ballot(v3 > 0.5f);
            if (lane == 0) {
                longlong4 w;
                w.x = (long long)b0; w.y = (long long)b1;
                w.z = (long long)b2; w.w = (long long)b3;
                *(longlong4*)(packed + tile * 4) = w;
            }
        }
        return;
    }

    // ---- block 0: init + sort + CSR + pairs ----
    __shared__ float sS[N];
    __shared__ int   orderS[N];
    __shared__ int   labS[N];
    __shared__ int   cnt[NC];
    __shared__ int   offs[NC + 1];
    __shared__ int   members[N];
    __shared__ int   pcnt;

    if (t == 0) { counters[0] = 0; pcnt = 0; }   // done-ticket for node 2
    if (t < N) sS[t] = scores[t];
    if (t < NC) cnt[t] = 0;
    __syncthreads();
    if (t < N) {                       // stable descending rank sort
        float si = sS[t];
        int rank = 0;
        for (int j = 0; j < N; ++j) {
            float sj = sS[j];
            if (sj > si || (sj == si && j < t)) rank++;
        }
        orderS[rank] = t;
    }
    __syncthreads();
    int myLab = -1;
    if (t < N) {
        int o = orderS[t];
        order_g[t]   = o;
        scoresS_g[t] = sS[o];
        myLab = labels[o];
        labS[t] = myLab;
        labelsS_g[t] = myLab;
    }
    __syncthreads();
    if (t < N) atomicAdd(&cnt[myLab], 1);
    __syncthreads();
    if (t == 0) {
        int s = 0;
        for (int c = 0; c < NC; ++c) { offs[c] = s; s += cnt[c]; }
        offs[NC] = s;
    }
    __syncthreads();
    if (t < NC) cnt[t] = offs[t];      // insertion cursors
    __syncthreads();
    if (t < N) { int p = atomicAdd(&cnt[myLab], 1); members[p] = t; }
    __syncthreads();
    if (t < NC) {                      // enumerate same-class pairs (i<j)
        int b = offs[t], e = offs[t + 1];
        for (int a = b; a < e; ++a)
            for (int c2 = a + 1; c2 < e; ++c2) {
                int i = members[a], j = members[c2];
                int lo = min(i, j), hi = max(i, j);
                int p = atomicAdd(&pcnt, 1);
                pairList[p] = make_int2(lo, hi);
            }
    }
    __syncthreads();
    if (t <= NC) offs_g[t] = offs[t];
    if (t < N)   members_g[t] = members[t];
    if (t == 0)  counters[1] = pcnt;   // pairCount
}

// ---------------------------------------------------------------------------
// Node 2. 64 blocks: IoU stripes with LLC-coherent atomic stores; after a
// vmcnt drain, a done-ticket elects the last block to run decay + final sort.
__global__ void __launch_bounds__(512)
k_ioudecay(const ull* __restrict__ packed, const int* __restrict__ order_g,
           const float* __restrict__ scoresS_g, const int* __restrict__ labelsS_g,
           const int* __restrict__ offs_g, const int* __restrict__ members_g,
           const int2* __restrict__ pairList, int* __restrict__ counters,
           int* __restrict__ iouI, int* __restrict__ keepOrig_g,
           float* __restrict__ outScores, float* __restrict__ outLabels,
           float* __restrict__ outKeep) {
    const int t    = threadIdx.x;
    const int lane = t & 63;
    __shared__ int sLast;

    // ---- IoU stripes (wave per pair) ----
    int np = counters[1];              // node-1 data (dispatch boundary)
    for (int p = (int)blockIdx.x * 8 + (t >> 6); p < np; p += IOUB * 8) {
        int2 pr = pairList[p];
        const ull* A = packed + (size_t)order_g[pr.x] * NW;
        const ull* B = packed + (size_t)order_g[pr.y] * NW;
        ull acc = 0;  // inter | areaA<<21 | areaB<<42  (fields < 2^17)
        for (int w = lane; w < NW; w += 64) {
            ull a = A[w], b = B[w];
            acc += (ull)__popcll(a & b)
                 + ((ull)__popcll(a) << 21)
                 + ((ull)__popcll(b) << 42);
        }
#pragma unroll
        for (int off = 32; off > 0; off >>= 1) acc += __shfl_down(acc, off, 64);
        if (lane == 0) {
            float inter = (float)(int)(acc & 0x1FFFFF);
            float areaA = (float)(int)((acc >> 21) & 0x1FFFFF);
            float areaB = (float)(int)((acc >> 42) & 0x1FFFFF);
            float uni   = areaA + areaB - inter;    // exact small ints
            __hip_atomic_store(iouI + pr.x * N + pr.y,
                               __float_as_int(inter / uni),
                               __ATOMIC_RELAXED, __HIP_MEMORY_SCOPE_AGENT);
        }
    }
    asm volatile("s_waitcnt vmcnt(0)" ::: "memory");   // stores at LLC
    __syncthreads();                                    // all waves drained
    if (t == 0) sLast = __hip_atomic_fetch_add(counters, 1, __ATOMIC_RELAXED,
                                               __HIP_MEMORY_SCOPE_AGENT);
    __syncthreads();
    if (sLast != IOUB - 1) return;

    // ---- decay + final stable sort (elected block) ----
    __shared__ int   labS[N];
    __shared__ float compS[N];
    __shared__ float sdec[N];
    __shared__ int   offs[NC + 1];
    __shared__ int   members[N];
    if (t < N)  { labS[t] = labelsS_g[t]; members[t] = members_g[t]; }
    if (t <= NC) offs[t] = offs_g[t];
    __syncthreads();
    if (t < N) {                        // comp[j] = max_{i<j same class} iou
        int lj = labS[t];
        float m = 0.f;
        int b = offs[lj], e = offs[lj + 1];
        for (int q = b; q < e; ++q) {
            int i = members[q];
            if (i < t) {
                float v = __int_as_float(__hip_atomic_load(
                    iouI + i * N + t, __ATOMIC_RELAXED, __HIP_MEMORY_SCOPE_AGENT));
                m = fmaxf(m, v);
            }
        }
        compS[t] = m;
    }
    __syncthreads();
    if (t < N) {                        // coefficient (1 bounds the min)
        int lj = labS[t];
        float c = 1.f;
        int b = offs[lj], e = offs[lj + 1];
        for (int q = b; q < e; ++q) {
            int i = members[q];
            if (i < t) {
                float d = __int_as_float(__hip_atomic_load(
                    iouI + i * N + t, __ATOMIC_RELAXED, __HIP_MEMORY_SCOPE_AGENT));
                float ci = compS[i];
                c = fminf(c, expf(-2.f * d * d) / expf(-2.f * ci * ci));  // mirror np
            }
        }
        sdec[t] = scoresS_g[t] * c;
    }
    __syncthreads();
    if (t < N) {                        // stable descending rank on decayed scores
        float sj = sdec[t];
        int rank = 0;
        for (int i = 0; i < N; ++i) {
            float si = sdec[i];
            if (si > sj || (si == sj && i < t)) rank++;
        }
        int o = order_g[t];
        outScores[rank]  = sj;
        outLabels[rank]  = (float)labS[t];
        outKeep[rank]    = (float)o;
        keepOrig_g[rank] = o;
    }
}

// ---------------------------------------------------------------------------
// Node 3. Expand kept masks to float output. 2D grid; nontemporal stores
// keep the 121.6 MB write-once stream out of L2.
__global__ void k_gather(const ull* __restrict__ packed, const int* __restrict__ keepOrig,
                         f32x4* __restrict__ outMasks) {
    int q = blockIdx.x * blockDim.x + threadIdx.x;   // quad within instance
    if (q >= HW / 4) return;
    int k    = blockIdx.y;
    int orig = keepOrig[k];                          // uniform -> scalar load
    ull w  = packed[(size_t)orig * NW + (q >> 4)];   // pix = q*4; word = pix>>6
    int sh = (q & 15) * 4;
    f32x4 r;
    r.x = (float)((w >> (sh    )) & 1ULL);
    r.y = (float)((w >> (sh + 1)) & 1ULL);
    r.z = (float)((w >> (sh + 2)) & 1ULL);
    r.w = (float)((w >> (sh + 3)) & 1ULL);
    __builtin_nontemporal_store(r, &outMasks[(size_t)k * (HW / 4) + q]);
}

// ---------------------------------------------------------------------------
extern "C" void kernel_launch(void* const* d_in, const int* in_sizes, int n_in,
                              void* d_out, int out_size, void* d_ws, size_t ws_size,
                              hipStream_t stream) {
    const float* mask_preds = (const float*)d_in[0];
    const int*   labels     = (const int*)d_in[1];
    const float* scores     = (const float*)d_in[2];

    float*  o         = (float*)d_out;
    float*  outScores = o;
    float*  outLabels = o + N;
    f32x4*  outMasks  = (f32x4*)(o + 2 * N);
    float*  outKeep   = o + 2 * N + (size_t)N * HW;

    // workspace carve-up (16B-aligned chunks; ~5.8 MB total)
    char* w = (char*)d_ws;
    ull*   packed     = (ull*)w;   w += (size_t)N * NW * 8;            // 3,800,000
    int*   order_g    = (int*)w;   w += N * 4;
    float* scoresS_g  = (float*)w; w += N * 4;
    int*   labelsS_g  = (int*)w;   w += N * 4;
    int*   offs_g     = (int*)w;   w += (NC + 4) * 4;
    int*   members_g  = (int*)w;   w += N * 4;
    int*   keepOrig_g = (int*)w;   w += N * 4;
    int*   counters   = (int*)w;   w += 128;   // done-ticket, pairCount
    int*   iouI       = (int*)w;   w += (size_t)N * N * 4;             // 1,000,000
    int2*  pairList   = (int2*)w;  /* N*(N-1)/2 * 8 = 998,000 */

    hipLaunchKernelGGL(k_packsort, dim3(PB + 1), dim3(512), 0, stream,
                       mask_preds, labels, scores, packed, order_g,
                       scoresS_g, labelsS_g, offs_g, members_g, pairList, counters);
    hipLaunchKernelGGL(k_ioudecay, dim3(IOUB), dim3(512), 0, stream,
                       packed, order_g, scoresS_g, labelsS_g, offs_g, members_g,
                       pairList, counters, iouI, keepOrig_g,
                       outScores, outLabels, outKeep);
    hipLaunchKernelGGL(k_gather, dim3(QPB, N), dim3(256), 0, stream,
                       packed, keepOrig_g, outMasks);
}

// Round 9
// 82.527 us; speedup vs baseline: 3.9291x; 1.2563x over previous
//
#include <hip/hip_runtime.h>

typedef unsigned long long ull;
typedef float f32x4 __attribute__((ext_vector_type(4)));

constexpr int N   = 500;
constexpr int HW  = 60800;    // 200*304
constexpr int NW  = 950;      // HW/64 (exact)
constexpr int NC  = 80;       // num classes
constexpr int NTILES = N * NW / 4;   // 118,750 pack tiles (256 px each)
constexpr int PB  = 1024;     // pack blocks (block 0 does the sort instead)
constexpr int IOUB = 256;     // IoU blocks in node 2 (R4-proven width)
constexpr int QPB = (HW / 4 + 255) / 256;   // 60 blocks of quads per instance

// ---------------------------------------------------------------------------
// Node 1. Block 0: stable score sort + per-class CSR + same-class pair list +
// ticket init.  Blocks 1..PB: binarize + bit-pack mask_preds.
__global__ void __launch_bounds__(512)
k_packsort(const float* __restrict__ mp, const int* __restrict__ labels,
           const float* __restrict__ scores,
           ull* __restrict__ packed, int* __restrict__ order_g,
           float* __restrict__ scoresS_g, int* __restrict__ labelsS_g,
           int* __restrict__ offs_g, int* __restrict__ members_g,
           int2* __restrict__ pairList, int* __restrict__ counters) {
    const int t    = threadIdx.x;
    const int lane = t & 63;

    if (blockIdx.x != 0) {
        // ---- pack ----
        int wid = (blockIdx.x - 1) * 8 + (t >> 6);
        for (int tile = wid; tile < NTILES; tile += PB * 8) {
            size_t base = (size_t)tile * 256;
            float v0 = mp[base +   0 + lane];
            float v1 = mp[base +  64 + lane];
            float v2 = mp[base + 128 + lane];
            float v3 = mp[base + 192 + lane];
            ull b0 = __ballot(v0 > 0.5f);
            ull b1 = __ballot(v1 > 0.5f);
            ull b2 = __ballot(v2 > 0.5f);
            ull b3 = __ballot(v3 > 0.5f);
            if (lane == 0) {
                longlong4 w;
                w.x = (long long)b0; w.y = (long long)b1;
                w.z = (long long)b2; w.w = (long long)b3;
                *(longlong4*)(packed + tile * 4) = w;
            }
        }
        return;
    }

    // ---- block 0: init + sort + CSR + pairs ----
    __shared__ float sS[N];
    __shared__ int   orderS[N];
    __shared__ int   labS[N];
    __shared__ int   cnt[NC];
    __shared__ int   offs[NC + 1];
    __shared__ int   members[N];
    __shared__ int   pcnt;

    if (t == 0) { counters[0] = 0; pcnt = 0; }   // done-ticket for node 2
    if (t < N) sS[t] = scores[t];
    if (t < NC) cnt[t] = 0;
    __syncthreads();
    if (t < N) {                       // stable descending rank sort
        float si = sS[t];
        int rank = 0;
        for (int j = 0; j < N; ++j) {
            float sj = sS[j];
            if (sj > si || (sj == si && j < t)) rank++;
        }
        orderS[rank] = t;
    }
    __syncthreads();
    int myLab = -1;
    if (t < N) {
        int o = orderS[t];
        order_g[t]   = o;
        scoresS_g[t] = sS[o];
        myLab = labels[o];
        labS[t] = myLab;
        labelsS_g[t] = myLab;
    }
    __syncthreads();
    if (t < N) atomicAdd(&cnt[myLab], 1);
    __syncthreads();
    if (t == 0) {
        int s = 0;
        for (int c = 0; c < NC; ++c) { offs[c] = s; s += cnt[c]; }
        offs[NC] = s;
    }
    __syncthreads();
    if (t < NC) cnt[t] = offs[t];      // insertion cursors
    __syncthreads();
    if (t < N) { int p = atomicAdd(&cnt[myLab], 1); members[p] = t; }
    __syncthreads();
    if (t < NC) {                      // enumerate same-class pairs (i<j)
        int b = offs[t], e = offs[t + 1];
        for (int a = b; a < e; ++a)
            for (int c2 = a + 1; c2 < e; ++c2) {
                int i = members[a], j = members[c2];
                int lo = min(i, j), hi = max(i, j);
                int p = atomicAdd(&pcnt, 1);
                pairList[p] = make_int2(lo, hi);
            }
    }
    __syncthreads();
    if (t <= NC) offs_g[t] = offs[t];
    if (t < N)   members_g[t] = members[t];
    if (t == 0)  counters[1] = pcnt;   // pairCount
}

// ---------------------------------------------------------------------------
// Node 2. 256 blocks: IoU stripes with LLC write-through atomic stores; after
// a vmcnt drain, a done-ticket elects the last block to run decay+final sort.
__global__ void __launch_bounds__(512)
k_ioudecay(const ull* __restrict__ packed, const int* __restrict__ order_g,
           const float* __restrict__ scoresS_g, const int* __restrict__ labelsS_g,
           const int* __restrict__ offs_g, const int* __restrict__ members_g,
           const int2* __restrict__ pairList, int* __restrict__ counters,
           int* __restrict__ iouI, int* __restrict__ keepOrig_g,
           float* __restrict__ outScores, float* __restrict__ outLabels,
           float* __restrict__ outKeep) {
    const int t    = threadIdx.x;
    const int lane = t & 63;
    __shared__ int sLast;

    // ---- IoU stripes (wave per pair) ----
    int np = counters[1];              // node-1 data (dispatch boundary)
    for (int p = (int)blockIdx.x * 8 + (t >> 6); p < np; p += IOUB * 8) {
        int2 pr = pairList[p];
        const ull* A = packed + (size_t)order_g[pr.x] * NW;
        const ull* B = packed + (size_t)order_g[pr.y] * NW;
        ull acc = 0;  // inter | areaA<<21 | areaB<<42  (fields < 2^17)
        for (int w = lane; w < NW; w += 64) {
            ull a = A[w], b = B[w];
            acc += (ull)__popcll(a & b)
                 + ((ull)__popcll(a) << 21)
                 + ((ull)__popcll(b) << 42);
        }
#pragma unroll
        for (int off = 32; off > 0; off >>= 1) acc += __shfl_down(acc, off, 64);
        if (lane == 0) {
            float inter = (float)(int)(acc & 0x1FFFFF);
            float areaA = (float)(int)((acc >> 21) & 0x1FFFFF);
            float areaB = (float)(int)((acc >> 42) & 0x1FFFFF);
            float uni   = areaA + areaB - inter;    // exact small ints
            __hip_atomic_store(iouI + pr.x * N + pr.y,
                               __float_as_int(inter / uni),
                               __ATOMIC_RELAXED, __HIP_MEMORY_SCOPE_AGENT);
        }
    }
    asm volatile("s_waitcnt vmcnt(0)" ::: "memory");   // stores at LLC
    __syncthreads();                                    // all waves drained
    if (t == 0) sLast = __hip_atomic_fetch_add(counters, 1, __ATOMIC_RELAXED,
                                               __HIP_MEMORY_SCOPE_AGENT);
    __syncthreads();
    if (sLast != IOUB - 1) return;

    // ---- decay + final stable sort (elected block) ----
    __shared__ int   labS[N];
    __shared__ float compS[N];
    __shared__ float sdec[N];
    __shared__ int   offs[NC + 1];
    __shared__ int   members[N];
    if (t < N)  { labS[t] = labelsS_g[t]; members[t] = members_g[t]; }
    if (t <= NC) offs[t] = offs_g[t];
    __syncthreads();
    if (t < N) {                        // comp[j] = max_{i<j same class} iou
        int lj = labS[t];
        float m = 0.f;
        int b = offs[lj], e = offs[lj + 1];
        for (int q = b; q < e; ++q) {
            int i = members[q];
            if (i < t) {
                float v = __int_as_float(__hip_atomic_load(
                    iouI + i * N + t, __ATOMIC_RELAXED, __HIP_MEMORY_SCOPE_AGENT));
                m = fmaxf(m, v);
            }
        }
        compS[t] = m;
    }
    __syncthreads();
    if (t < N) {                        // coefficient (1 bounds the min)
        int lj = labS[t];
        float c = 1.f;
        int b = offs[lj], e = offs[lj + 1];
        for (int q = b; q < e; ++q) {
            int i = members[q];
            if (i < t) {
                float d = __int_as_float(__hip_atomic_load(
                    iouI + i * N + t, __ATOMIC_RELAXED, __HIP_MEMORY_SCOPE_AGENT));
                float ci = compS[i];
                c = fminf(c, expf(-2.f * d * d) / expf(-2.f * ci * ci));  // mirror np
            }
        }
        sdec[t] = scoresS_g[t] * c;
    }
    __syncthreads();
    if (t < N) {                        // stable descending rank on decayed scores
        float sj = sdec[t];
        int rank = 0;
        for (int i = 0; i < N; ++i) {
            float si = sdec[i];
            if (si > sj || (si == sj && i < t)) rank++;
        }
        int o = order_g[t];
        outScores[rank]  = sj;
        outLabels[rank]  = (float)labS[t];
        outKeep[rank]    = (float)o;
        keepOrig_g[rank] = o;
    }
}

// ---------------------------------------------------------------------------
// Node 3. Expand kept masks to float output. 2D grid; plain coalesced
// f32x4 stores (R4-proven path).
__global__ void k_gather(const ull* __restrict__ packed, const int* __restrict__ keepOrig,
                         f32x4* __restrict__ outMasks) {
    int q = blockIdx.x * blockDim.x + threadIdx.x;   // quad within instance
    if (q >= HW / 4) return;
    int k    = blockIdx.y;
    int orig = keepOrig[k];                          // uniform -> scalar load
    ull w  = packed[(size_t)orig * NW + (q >> 4)];   // pix = q*4; word = pix>>6
    int sh = (q & 15) * 4;
    f32x4 r;
    r.x = (float)((w >> (sh    )) & 1ULL);
    r.y = (float)((w >> (sh + 1)) & 1ULL);
    r.z = (float)((w >> (sh + 2)) & 1ULL);
    r.w = (float)((w >> (sh + 3)) & 1ULL);
    outMasks[(size_t)k * (HW / 4) + q] = r;
}

// ---------------------------------------------------------------------------
extern "C" void kernel_launch(void* const* d_in, const int* in_sizes, int n_in,
                              void* d_out, int out_size, void* d_ws, size_t ws_size,
                              hipStream_t stream) {
    const float* mask_preds = (const float*)d_in[0];
    const int*   labels     = (const int*)d_in[1];
    const float* scores     = (const float*)d_in[2];

    float*  o         = (float*)d_out;
    float*  outScores = o;
    float*  outLabels = o + N;
    f32x4*  outMasks  = (f32x4*)(o + 2 * N);
    float*  outKeep   = o + 2 * N + (size_t)N * HW;

    // workspace carve-up (16B-aligned chunks; ~5.8 MB total)
    char* w = (char*)d_ws;
    ull*   packed     = (ull*)w;   w += (size_t)N * NW * 8;            // 3,800,000
    int*   order_g    = (int*)w;   w += N * 4;
    float* scoresS_g  = (float*)w; w += N * 4;
    int*   labelsS_g  = (int*)w;   w += N * 4;
    int*   offs_g     = (int*)w;   w += (NC + 4) * 4;
    int*   members_g  = (int*)w;   w += N * 4;
    int*   keepOrig_g = (int*)w;   w += N * 4;
    int*   counters   = (int*)w;   w += 128;   // done-ticket, pairCount
    int*   iouI       = (int*)w;   w += (size_t)N * N * 4;             // 1,000,000
    int2*  pairList   = (int2*)w;  /* N*(N-1)/2 * 8 = 998,000 */

    hipLaunchKernelGGL(k_packsort, dim3(PB + 1), dim3(512), 0, stream,
                       mask_preds, labels, scores, packed, order_g,
                       scoresS_g, labelsS_g, offs_g, members_g, pairList, counters);
    hipLaunchKernelGGL(k_ioudecay, dim3(IOUB), dim3(512), 0, stream,
                       packed, order_g, scoresS_g, labelsS_g, offs_g, members_g,
                       pairList, counters, iouI, keepOrig_g,
                       outScores, outLabels, outKeep);
    hipLaunchKernelGGL(k_gather, dim3(QPB, N), dim3(256), 0, stream,
                       packed, keepOrig_g, outMasks);
}